// Round 8
// baseline (933.947 us; speedup 1.0000x reference)
//
#include <hip/hip_runtime.h>

typedef unsigned short u16;
typedef unsigned int u32;
typedef unsigned char u8;

constexpr int NN = 100000;   // nodes
constexpr int NE = 1600000;  // edges
constexpr int H = 128;       // hidden

constexpr int NB = 196;      // coarse buckets: b = dst >> 9 (512 nodes/bucket)
constexpr int BCAP = 10240;  // per-bucket capacity (mean 8192, +22 sigma)
constexpr int PB_E = 4096;   // edges per partition block
constexpr int PB_BLOCKS = (NE + PB_E - 1) / PB_E;  // 391
constexpr int WT_BLOCKS = 512;
constexpr int XI_BLOCKS = (NN * H / 4) / 256;      // 12500

typedef __bf16 bf16x8 __attribute__((ext_vector_type(8)));
typedef float f32x16 __attribute__((ext_vector_type(16)));

__device__ __forceinline__ u16 f2bf(float f) {
    union { float f; u32 u; } cv; cv.f = f;
    u32 r = (cv.u + 0x7fffu + ((cv.u >> 16) & 1u)) >> 16;
    return (u16)r;
}
__device__ __forceinline__ float bflo(u32 u) {
    union { u32 u; float f; } cv; cv.u = u << 16; return cv.f;
}
__device__ __forceinline__ float bfhi(u32 u) {
    union { u32 u; float f; } cv; cv.u = u & 0xffff0000u; return cv.f;
}
__device__ __forceinline__ u32 pkbf(float a, float b) {
    return (u32)f2bf(a) | ((u32)f2bf(b) << 16);
}

// ---- fused preproc: edge partition / weight transpose / x init --------------
// blocks [0,391): LDS counting-sort partition of edges into NB dst-buckets.
// blocks [391,903): Wt[l*2+s][n][k] = W[l][k][n] (bf16)
// blocks [903,13403): x fp32 copy + COLUMN-SLICED bf16 shadow
// R13: xb is stored as 8 slices of 16 columns: xbs[s][node][16] (3.2MB/slice,
// fits one XCD's 4MB L2) so the new agg_kernel's random gather is L2-resident.
__global__ __launch_bounds__(256) void preproc_kernel(const int* __restrict__ e,
                                                      int* __restrict__ gcursor,
                                                      u32* __restrict__ ebuf,
                                                      const float* __restrict__ W1,
                                                      const float* __restrict__ W2,
                                                      u16* __restrict__ wt,
                                                      const float* __restrict__ xin,
                                                      float* __restrict__ x,
                                                      u16* __restrict__ xbs) {
    __shared__ int lcnt[256];
    __shared__ int ps[256];
    __shared__ int ex[256];
    __shared__ int gbaseL[NB];
    __shared__ int anynz;
    __shared__ u32 sbuf[PB_E];   // 16 KB
    __shared__ u8 sbk[PB_E];     // 4 KB
    const int blk = blockIdx.x;
    const int t = threadIdx.x;

    if (blk >= PB_BLOCKS) {
        if (blk < PB_BLOCKS + WT_BLOCKS) {
            int tt = (blk - PB_BLOCKS) * 256 + t;  // 131072 threads
            int w = tt >> 14;      // 0..7 = l*2+s
            int r = tt & 16383;
            int k = r >> 7, n = r & 127;  // n fastest -> coalesced reads
            int l = w >> 1, s = w & 1;
            const float* src = (s == 0 ? W1 : W2) + l * 16384;
            wt[w * 16384 + n * 128 + k] = f2bf(src[k * 128 + n]);
        } else {
            int i = (blk - PB_BLOCKS - WT_BLOCKS) * 256 + t;  // NN*H/4 threads
            float4 v = ((const float4*)xin)[i];
            ((float4*)x)[i] = v;
            int n = i >> 5;      // node
            int j = i & 31;      // float4 index in row: cols j*4..j*4+3
            u32* dst = (u32*)xbs + (size_t)(j >> 2) * (NN * 8) + n * 8 + (j & 3) * 2;
            ((uint2*)dst)[0] = make_uint2(pkbf(v.x, v.y), pkbf(v.z, v.w));
        }
        return;
    }

    // ---- edge partition branch (LDS counting sort) ----
    if (t == 0) anynz = 0;
    lcnt[t] = 0;
    __syncthreads();
    int loc = 0;
    for (int i = t; i < 4096; i += 256) loc |= e[2 * i + 1];
    if (loc) atomicOr(&anynz, 1);
    __syncthreads();
    const int st = anynz ? 1 : 2;  // stride in int32 units (int32 vs int64 input)
    const int base = blk * PB_E;
    const int nval = (NE - base < PB_E) ? (NE - base) : PB_E;
    u32 pk[16]; int bk[16]; int rk[16];
#pragma unroll
    for (int j = 0; j < 16; ++j) {
        int i = base + j * 256 + t;
        bk[j] = -1;
        if (i < NE) {
            int s = e[st * i];
            int d = e[st * (NE + i)];
            int b = d >> 9;
            pk[j] = (u32)s | ((u32)(d & 511) << 17);
            bk[j] = b;
            rk[j] = atomicAdd(&lcnt[b], 1);
        }
    }
    __syncthreads();
    int v = lcnt[t];
    ps[t] = v;
    __syncthreads();
    for (int off = 1; off < 256; off <<= 1) {
        int u = (t >= off) ? ps[t - off] : 0;
        __syncthreads();
        ps[t] += u;
        __syncthreads();
    }
    ex[t] = ps[t] - v;
    if (t < NB && v > 0) gbaseL[t] = atomicAdd(&gcursor[t], v);
    __syncthreads();
#pragma unroll
    for (int j = 0; j < 16; ++j)
        if (bk[j] >= 0) {
            int p = ex[bk[j]] + rk[j];
            sbuf[p] = pk[j];
            sbk[p] = (u8)bk[j];
        }
    __syncthreads();
    for (int i = t; i < nval; i += 256) {
        int b = sbk[i];
        ebuf[b * BCAP + gbaseL[b] + (i - ex[b])] = sbuf[i];
    }
}

// ---- per-bucket CSR fill (bscan folded in: each block scans the 196 counts) -
__global__ __launch_bounds__(256) void bfill_kernel(const u32* __restrict__ ebuf,
                                                    const int* __restrict__ gcursor,
                                                    int* __restrict__ offs,
                                                    int* __restrict__ colv) {
    __shared__ int ncnt[512];
    __shared__ int cur[512];
    __shared__ int ps[256];
    const int b = blockIdx.x, t = threadIdx.x;
    const int En = gcursor[b];
    int gv = (t < NB) ? gcursor[t] : 0;
    ps[t] = gv;
    __syncthreads();
    for (int off = 1; off < 256; off <<= 1) {
        int u = (t >= off) ? ps[t - off] : 0;
        __syncthreads();
        ps[t] += u;
        __syncthreads();
    }
    const int bb = ps[b] - En;  // exclusive prefix of this bucket
    if (b == 0 && t == 0) offs[NN] = NE;
    ncnt[t] = 0; ncnt[t + 256] = 0;
    __syncthreads();
    const u32* eb = ebuf + b * BCAP;
    for (int i = t; i < En; i += 256)
        atomicAdd(&ncnt[eb[i] >> 17], 1);
    __syncthreads();
    int s2 = ncnt[2 * t] + ncnt[2 * t + 1];
    ps[t] = s2;
    __syncthreads();
    for (int off = 1; off < 256; off <<= 1) {
        int u = (t >= off) ? ps[t - off] : 0;
        __syncthreads();
        ps[t] += u;
        __syncthreads();
    }
    int e0 = ps[t] - s2;  // exclusive
    cur[2 * t] = e0;
    cur[2 * t + 1] = e0 + ncnt[2 * t];
    __syncthreads();
    const int n0 = b * 512;
    for (int i = t; i < 512; i += 256)
        if (n0 + i < NN) offs[n0 + i] = bb + cur[i];
    __syncthreads();
    for (int i = t; i < En; i += 256) {
        u32 p = eb[i];
        int pos = atomicAdd(&cur[p >> 17], 1);
        colv[bb + pos] = (int)(p & 0x1FFFFu);
    }
}

// ---- column-sliced aggregation ----------------------------------------------
// R13: grid = (NN/32) node-tiles x 8 col-slices; slice = blockIdx&7 so the
// round-robin block->XCD dispatch pins slice c to XCD c: the random per-edge
// gather reads a 3.2MB L2-RESIDENT slice (was: 256B rows missing L2, filled
// over the fabric at ~2.5 TB/s — the measured bottleneck of R5-R7).
// Octet (8 lanes) walks one node's edge list; 8 u32 = 16 cols per edge; colv
// read nontemporally (don't evict the slice); output streamed nontemporally.
__global__ __launch_bounds__(256) void agg_kernel(const u16* __restrict__ xbsin,
                                                  const int* __restrict__ colv,
                                                  const int* __restrict__ offs,
                                                  u16* __restrict__ aggb) {
    const int cg = blockIdx.x & 7;
    const int tile = blockIdx.x >> 3;
    const int lane = threadIdx.x & 63;
    const int wave = threadIdx.x >> 6;
    const int o = lane >> 3, cl = lane & 7;
    const int n = tile * 32 + wave * 8 + o;
    const u32* slice = (const u32*)xbsin + (size_t)cg * (NN * 8);
    const int jb = offs[n];
    const int je = offs[n + 1];
    u32 sv = slice[n * 8 + cl];            // self term (GIN: +x_i)
    float a0 = bflo(sv), a1 = bfhi(sv);
    for (int j = jb; j < je; j += 8) {
        int src[8]; u32 mk[8];
#pragma unroll
        for (int q = 0; q < 8; ++q) {
            int idx = j + q < je ? j + q : je - 1;  // clamp: dup of last edge
            mk[q] = (j + q < je) ? 0xffffffffu : 0u;
            src[q] = __builtin_nontemporal_load(colv + idx) & 0x1FFFF;
        }
        u32 vv[8];
#pragma unroll
        for (int q = 0; q < 8; ++q) vv[q] = slice[src[q] * 8 + cl];
#pragma unroll
        for (int q = 0; q < 8; ++q) {
            u32 u = vv[q] & mk[q];
            a0 += bflo(u); a1 += bfhi(u);
        }
    }
    __builtin_nontemporal_store(pkbf(a0, a1),
                                (u32*)aggb + (size_t)cg * (NN * 8) + n * 8 + cl);
}

// ---- MLP: pure streaming + GEMM (gather removed) ----------------------------
// Reads the sliced agg tile, runs the two 32x128x128 GEMMs, fp32 x RMW
// (streaming bytes are hidden under other traffic — R6/R7 evidence), writes
// the next layer's sliced bf16 shadow.
__global__ __launch_bounds__(256) void mlp_kernel(const u16* __restrict__ aggb,
                                                  const u16* __restrict__ wt1,
                                                  const u16* __restrict__ wt2,
                                                  const float* __restrict__ b1,
                                                  const float* __restrict__ b2,
                                                  float* __restrict__ x,
                                                  u16* __restrict__ xbsout) {
    __shared__ u16 lds[32 * 128];  // 8 KB, XOR-swizzled 16B chunks
    const int tid = threadIdx.x;
    const int wave = tid >> 6, lane = tid & 63;
    const int ml = lane & 31, g = lane >> 5;
    const int row0 = blockIdx.x * 32;  // NN = 3125*32 exactly, no tail

    // Phase 0: sliced agg tile -> LDS (per wave: 8 slices x 128B contiguous)
#pragma unroll
    for (int i = 0; i < 2; ++i) {
        int ch = tid + 256 * i;
        int r = ch >> 4, c = ch & 15;
        const u16* src = aggb + (size_t)(c >> 1) * (NN * 16) + (row0 + r) * 16 + (c & 1) * 8;
        int4 v = *(const int4*)src;
        *(int4*)(&lds[r * H + ((c ^ (r & 15)) << 3)]) = v;
    }

    // B1 fragments + biases
    bf16x8 bfrag[8];
#pragma unroll
    for (int ks = 0; ks < 8; ++ks)
        bfrag[ks] = *(const bf16x8*)(wt1 + (wave * 32 + ml) * H + ks * 16 + g * 8);
    const float bias1 = b1[wave * 32 + ml];
    const float bias2 = b2[wave * 32 + ml];

    __syncthreads();

    f32x16 acc;
#pragma unroll
    for (int i = 0; i < 16; ++i) acc[i] = 0.f;

    // GEMM1: C[0:32][wave*32 .. +32]
#pragma unroll
    for (int ks = 0; ks < 8; ++ks) {
        int chunk = (2 * ks + g) ^ (ml & 15);
        bf16x8 afrag = *(const bf16x8*)(&lds[ml * H + (chunk << 3)]);
        acc = __builtin_amdgcn_mfma_f32_32x32x16_bf16(afrag, bfrag[ks], acc, 0, 0, 0);
    }

    __syncthreads();  // all A reads done before T overwrites LDS

    // T = relu(acc + b1) -> LDS (C-layout -> row-major[m][k], swizzled)
#pragma unroll
    for (int reg = 0; reg < 16; ++reg) {
        int rm = (reg & 3) + ((reg >> 2) << 3) + 4 * g;   // 0..31
        int cn = wave * 32 + ml;                           // 0..127
        float v = acc[reg] + bias1;
        v = v > 0.f ? v : 0.f;
        lds[rm * H + ((((cn >> 3) ^ (rm & 15))) << 3) + (cn & 7)] = f2bf(v);
    }

    // B2 fragments
#pragma unroll
    for (int ks = 0; ks < 8; ++ks)
        bfrag[ks] = *(const bf16x8*)(wt2 + (wave * 32 + ml) * H + ks * 16 + g * 8);

#pragma unroll
    for (int i = 0; i < 16; ++i) acc[i] = 0.f;

    __syncthreads();

    // GEMM2
#pragma unroll
    for (int ks = 0; ks < 8; ++ks) {
        int chunk = (2 * ks + g) ^ (ml & 15);
        bf16x8 afrag = *(const bf16x8*)(&lds[ml * H + (chunk << 3)]);
        acc = __builtin_amdgcn_mfma_f32_32x32x16_bf16(afrag, bfrag[ks], acc, 0, 0, 0);
    }

    __syncthreads();  // all T reads done before h overwrites LDS

    // h = relu(acc + b2) -> LDS (same swizzle)
#pragma unroll
    for (int reg = 0; reg < 16; ++reg) {
        int rm = (reg & 3) + ((reg >> 2) << 3) + 4 * g;
        int cn = wave * 32 + ml;
        float v = acc[reg] + bias2;
        v = v > 0.f ? v : 0.f;
        lds[rm * H + ((((cn >> 3) ^ (rm & 15))) << 3) + (cn & 7)] = f2bf(v);
    }

    __syncthreads();

    // epilogue: x += relu(h) (fp32 RMW); xbsout = bf16(x) sliced
#pragma unroll
    for (int i = 0; i < 2; ++i) {
        int ch = tid + 256 * i;
        int r = ch >> 4, c = ch & 15;
        int gr = row0 + r;
        int4 hv = *(const int4*)(&lds[r * H + ((c ^ (r & 15)) << 3)]);
        float4 x0 = *(const float4*)(x + gr * H + c * 8);
        float4 x1 = *(const float4*)(x + gr * H + c * 8 + 4);
        x0.x += bflo((u32)hv.x); x0.y += bfhi((u32)hv.x);
        x0.z += bflo((u32)hv.y); x0.w += bfhi((u32)hv.y);
        x1.x += bflo((u32)hv.z); x1.y += bfhi((u32)hv.z);
        x1.z += bflo((u32)hv.w); x1.w += bfhi((u32)hv.w);
        *(float4*)(x + gr * H + c * 8) = x0;
        *(float4*)(x + gr * H + c * 8 + 4) = x1;
        int4 xo;
        xo.x = (int)pkbf(x0.x, x0.y);
        xo.y = (int)pkbf(x0.z, x0.w);
        xo.z = (int)pkbf(x1.x, x1.y);
        xo.w = (int)pkbf(x1.z, x1.w);
        *(int4*)(xbsout + (size_t)(c >> 1) * (NN * 16) + gr * 16 + (c & 1) * 8) = xo;
    }
}

extern "C" void kernel_launch(void* const* d_in, const int* in_sizes, int n_in,
                              void* d_out, int out_size, void* d_ws, size_t ws_size,
                              hipStream_t stream) {
    const float* x_in = (const float*)d_in[0];
    const int* edges = (const int*)d_in[1];
    const float* W1 = (const float*)d_in[2];
    const float* b1 = (const float*)d_in[3];
    const float* W2 = (const float*)d_in[4];
    const float* b2 = (const float*)d_in[5];
    float* x = (float*)d_out;

    char* ws = (char*)d_ws;
    int* gcursor = (int*)(ws + 512);             // 784B      @ 512
    int* offs = (int*)(ws + 4096);               // 400004B   @ 4096
    int* colv = (int*)(ws + 406528);             // 6400000B
    u16* wt = (u16*)(ws + 6809600);              // 262144B
    u16* xbs0 = (u16*)(ws + 7072768);            // 25600000B (8 col-slices)
    u16* xbs1 = (u16*)(ws + 32672768);           // 25600000B
    u16* aggb = (u16*)(ws + 58272768);           // 25600000B (end 83.9MB; R6 ran at this size)
    u32* ebuf = (u32*)aggb;                      // 8.03MB, dead before aggb written

    hipMemsetAsync(gcursor, 0, NB * sizeof(int), stream);
    preproc_kernel<<<PB_BLOCKS + WT_BLOCKS + XI_BLOCKS, 256, 0, stream>>>(
        edges, gcursor, ebuf, W1, W2, wt, x_in, x, xbs0);
    bfill_kernel<<<NB, 256, 0, stream>>>(ebuf, gcursor, offs, colv);

    for (int l = 0; l < 4; ++l) {
        u16* xin = (l & 1) ? xbs1 : xbs0;
        u16* xout = (l & 1) ? xbs0 : xbs1;
        agg_kernel<<<(NN / 32) * 8, 256, 0, stream>>>(xin, colv, offs, aggb);
        mlp_kernel<<<NN / 32, 256, 0, stream>>>(
            aggb, wt + (l * 2) * 16384, wt + (l * 2 + 1) * 16384,
            b1 + l * 128, b2 + l * 128, x, xout);
    }
}

// Round 9
// 460.520 us; speedup vs baseline: 2.0280x; 2.0280x over previous
//
#include <hip/hip_runtime.h>

typedef unsigned short u16;
typedef unsigned int u32;
typedef unsigned char u8;

constexpr int NN = 100000;   // nodes
constexpr int NE = 1600000;  // edges
constexpr int H = 128;       // hidden

constexpr int NB = 196;      // coarse buckets: b = dst >> 9 (512 nodes/bucket)
constexpr int BCAP = 10240;  // per-bucket capacity (mean 8192, +22 sigma)
constexpr int PB_E = 4096;   // edges per partition block
constexpr int PB_BLOCKS = (NE + PB_E - 1) / PB_E;  // 391
constexpr int WT_BLOCKS = 512;
constexpr int XI_BLOCKS = (NN * H / 4) / 256;      // 12500

typedef __bf16 bf16x8 __attribute__((ext_vector_type(8)));
typedef float f32x16 __attribute__((ext_vector_type(16)));

__device__ __forceinline__ u16 f2bf(float f) {
    union { float f; u32 u; } cv; cv.f = f;
    u32 r = (cv.u + 0x7fffu + ((cv.u >> 16) & 1u)) >> 16;
    return (u16)r;
}
__device__ __forceinline__ float bflo(u32 u) {
    union { u32 u; float f; } cv; cv.u = u << 16; return cv.f;
}
__device__ __forceinline__ float bfhi(u32 u) {
    union { u32 u; float f; } cv; cv.u = u & 0xffff0000u; return cv.f;
}
__device__ __forceinline__ u32 pkbf(float a, float b) {
    return (u32)f2bf(a) | ((u32)f2bf(b) << 16);
}

// ---- fused preproc: edge partition / weight transpose / xb init -------------
// R14: x fp32 copy REMOVED (layer-0 mlp reads x_in directly as its residual
// base) — saves 51.2MB of preproc writes. R8 post-mortem: column-slicing the
// gather wins on bytes (FETCH 196->57MB) but loses 2x on the request path
// (8-way-scattered wave loads); R7's row-per-wave fused gather at ~3.5TB/s is
// the bf16 structural floor, so R7's mlp body is restored unchanged.
// blocks [0,391): LDS counting-sort partition of edges into NB dst-buckets.
// blocks [391,903): Wt[l*2+s][n][k] = W[l][k][n] (bf16)
// blocks [903,13403): xb bf16 shadow init
__global__ __launch_bounds__(256) void preproc_kernel(const int* __restrict__ e,
                                                      int* __restrict__ gcursor,
                                                      u32* __restrict__ ebuf,
                                                      const float* __restrict__ W1,
                                                      const float* __restrict__ W2,
                                                      u16* __restrict__ wt,
                                                      const float* __restrict__ xin,
                                                      u16* __restrict__ xb) {
    __shared__ int lcnt[256];
    __shared__ int ps[256];
    __shared__ int ex[256];
    __shared__ int gbaseL[NB];
    __shared__ int anynz;
    __shared__ u32 sbuf[PB_E];   // 16 KB
    __shared__ u8 sbk[PB_E];     // 4 KB
    const int blk = blockIdx.x;
    const int t = threadIdx.x;

    if (blk >= PB_BLOCKS) {
        if (blk < PB_BLOCKS + WT_BLOCKS) {
            int tt = (blk - PB_BLOCKS) * 256 + t;  // 131072 threads
            int w = tt >> 14;      // 0..7 = l*2+s
            int r = tt & 16383;
            int k = r >> 7, n = r & 127;  // n fastest -> coalesced reads
            int l = w >> 1, s = w & 1;
            const float* src = (s == 0 ? W1 : W2) + l * 16384;
            wt[w * 16384 + n * 128 + k] = f2bf(src[k * 128 + n]);
        } else {
            int i = (blk - PB_BLOCKS - WT_BLOCKS) * 256 + t;  // NN*H/4 threads
            float4 v = ((const float4*)xin)[i];
            uint2 p;
            p.x = pkbf(v.x, v.y);
            p.y = pkbf(v.z, v.w);
            ((uint2*)xb)[i] = p;
        }
        return;
    }

    // ---- edge partition branch (LDS counting sort) ----
    if (t == 0) anynz = 0;
    lcnt[t] = 0;
    __syncthreads();
    int loc = 0;
    for (int i = t; i < 4096; i += 256) loc |= e[2 * i + 1];
    if (loc) atomicOr(&anynz, 1);
    __syncthreads();
    const int st = anynz ? 1 : 2;  // stride in int32 units (int32 vs int64 input)
    const int base = blk * PB_E;
    const int nval = (NE - base < PB_E) ? (NE - base) : PB_E;
    u32 pk[16]; int bk[16]; int rk[16];
#pragma unroll
    for (int j = 0; j < 16; ++j) {
        int i = base + j * 256 + t;
        bk[j] = -1;
        if (i < NE) {
            int s = e[st * i];
            int d = e[st * (NE + i)];
            int b = d >> 9;
            pk[j] = (u32)s | ((u32)(d & 511) << 17);
            bk[j] = b;
            rk[j] = atomicAdd(&lcnt[b], 1);
        }
    }
    __syncthreads();
    int v = lcnt[t];
    ps[t] = v;
    __syncthreads();
    for (int off = 1; off < 256; off <<= 1) {
        int u = (t >= off) ? ps[t - off] : 0;
        __syncthreads();
        ps[t] += u;
        __syncthreads();
    }
    ex[t] = ps[t] - v;
    if (t < NB && v > 0) gbaseL[t] = atomicAdd(&gcursor[t], v);
    __syncthreads();
#pragma unroll
    for (int j = 0; j < 16; ++j)
        if (bk[j] >= 0) {
            int p = ex[bk[j]] + rk[j];
            sbuf[p] = pk[j];
            sbk[p] = (u8)bk[j];
        }
    __syncthreads();
    for (int i = t; i < nval; i += 256) {
        int b = sbk[i];
        ebuf[b * BCAP + gbaseL[b] + (i - ex[b])] = sbuf[i];
    }
}

// ---- per-bucket CSR fill (bscan folded; R14: 1024 threads/block, 4x the
// per-pass width — 196x256 was <1 block/CU) --------------------------------
// colv entry packs src (bits 0..16) and tile-local dst row (bits 27..31).
__global__ __launch_bounds__(1024) void bfill_kernel(const u32* __restrict__ ebuf,
                                                     const int* __restrict__ gcursor,
                                                     int* __restrict__ offs,
                                                     int* __restrict__ colv) {
    __shared__ int ncnt[512];
    __shared__ int cur[512];
    __shared__ int ps[256];
    const int b = blockIdx.x, t = threadIdx.x;
    const int En = gcursor[b];
    // exclusive scan of bucket totals -> bb (threads t<256 active)
    if (t < 256) ps[t] = (t < NB) ? gcursor[t] : 0;
    __syncthreads();
    for (int off = 1; off < 256; off <<= 1) {
        int u = 0;
        if (t < 256 && t >= off) u = ps[t - off];
        __syncthreads();
        if (t < 256) ps[t] += u;
        __syncthreads();
    }
    const int bb = ps[b] - En;  // exclusive prefix of this bucket
    if (b == 0 && t == 0) offs[NN] = NE;
    if (t < 512) ncnt[t] = 0;
    __syncthreads();
    const u32* eb = ebuf + b * BCAP;
    for (int i = t; i < En; i += 1024)
        atomicAdd(&ncnt[eb[i] >> 17], 1);
    __syncthreads();
    int s2 = 0;
    if (t < 256) { s2 = ncnt[2 * t] + ncnt[2 * t + 1]; ps[t] = s2; }
    __syncthreads();
    for (int off = 1; off < 256; off <<= 1) {
        int u = 0;
        if (t < 256 && t >= off) u = ps[t - off];
        __syncthreads();
        if (t < 256) ps[t] += u;
        __syncthreads();
    }
    if (t < 256) {
        int e0 = ps[t] - s2;  // exclusive
        cur[2 * t] = e0;
        cur[2 * t + 1] = e0 + ncnt[2 * t];
    }
    __syncthreads();
    const int n0 = b * 512;
    if (t < 512 && n0 + t < NN) offs[n0 + t] = bb + cur[t];
    __syncthreads();  // offs reads of cur[] complete before pass2 mutates
    for (int i = t; i < En; i += 1024) {
        u32 p = eb[i];
        int pos = atomicAdd(&cur[p >> 17], 1);
        colv[bb + pos] = (int)((p & 0x1FFFFu) | (((p >> 17) & 31u) << 27));
    }
}

// ---- fused layer: agg (gather into LDS) + MLP + residual --------------------
// R7 body verbatim (84.8us measured): flat-range 16-deep gather with colv
// prefetch, wave-uniform row routing (colv bits 27..31), LDS pre-filled with
// self rows, B-fragments AFTER the gather, fp32 residual RMW epilogue.
// R14: residual base read from xr (x_in for layer 0, x for layers 1-3) so
// preproc need not copy x_in -> x.
__global__ __launch_bounds__(256) void mlp_kernel(const u16* __restrict__ xbin,
                                                  const int* __restrict__ colv,
                                                  const int* __restrict__ offs,
                                                  const u16* __restrict__ wt1,
                                                  const u16* __restrict__ wt2,
                                                  const float* __restrict__ b1,
                                                  const float* __restrict__ b2,
                                                  const float* __restrict__ xr,
                                                  float* __restrict__ xw,
                                                  u16* __restrict__ xbout) {
    __shared__ u16 lds[32 * 128];  // 8 KB, XOR-swizzled 16B chunks
    const int tid = threadIdx.x;
    const int wave = tid >> 6, lane = tid & 63;
    const int ml = lane & 31, g = lane >> 5;
    const int row0 = blockIdx.x * 32;  // NN = 3125*32 exactly, no tail

    // Phase 0a: self rows -> LDS (coalesced int4, swizzled)
#pragma unroll
    for (int i = 0; i < 2; ++i) {
        int ch = tid + 256 * i;
        int r = ch >> 4, c = ch & 15;
        int gr = row0 + r;
        int4 v = *(const int4*)(xbin + gr * H + c * 8);
        *(int4*)(&lds[r * H + ((c ^ (r & 15)) << 3)]) = v;
    }
    __syncthreads();  // waves flush rows filled by other waves' threads

    // Phase 0b: flat-range gather, accumulate into LDS rows
    {
        const int node0 = row0 + wave * 8;
        const int jb = __builtin_amdgcn_readfirstlane(offs[node0]);
        const int je = __builtin_amdgcn_readfirstlane(offs[node0 + 8]);
        int cur = wave * 8;          // current tile-local row (monotone)
        float a0 = 0.f, a1 = 0.f;
        if (jb < je) {
            u32 ce[16];
#pragma unroll
            for (int q = 0; q < 16; ++q) {
                int idx = jb + q;
                idx = idx < je ? idx : je - 1;
                ce[q] = (u32)__builtin_amdgcn_readfirstlane(colv[idx]);
            }
            for (int j = jb; j < je; j += 16) {
                u32 uu[16];
#pragma unroll
                for (int q = 0; q < 16; ++q)
                    uu[q] = *(const u32*)(xbin + (ce[q] & 0x1FFFFu) * H + lane * 2);
                u32 cn[16];  // prefetch next window's colv entries
#pragma unroll
                for (int q = 0; q < 16; ++q) {
                    int idx = j + 16 + q;
                    idx = idx < je ? idx : je - 1;
                    cn[q] = (u32)__builtin_amdgcn_readfirstlane(colv[idx]);
                }
#pragma unroll
                for (int q = 0; q < 16; ++q) {
                    if (j + q < je) {  // wave-uniform
                        int rloc = (int)(ce[q] >> 27);
                        if (rloc != cur) {  // flush completed row (once per row)
                            u16* p = &lds[cur * H + (((lane >> 2) ^ (cur & 15)) << 3) + ((lane & 3) << 1)];
                            u32 old = *(u32*)p;
                            *(u32*)p = pkbf(bflo(old) + a0, bfhi(old) + a1);
                            a0 = 0.f; a1 = 0.f; cur = rloc;
                        }
                        a0 += bflo(uu[q]); a1 += bfhi(uu[q]);
                    }
                }
#pragma unroll
                for (int q = 0; q < 16; ++q) ce[q] = cn[q];
            }
        }
        // final flush (adds 0 if range empty — harmless)
        u16* p = &lds[cur * H + (((lane >> 2) ^ (cur & 15)) << 3) + ((lane & 3) << 1)];
        u32 old = *(u32*)p;
        *(u32*)p = pkbf(bflo(old) + a0, bfhi(old) + a1);
    }

    // B1 fragments + biases (after gather — R5 hoist regressed)
    bf16x8 bfrag[8];
#pragma unroll
    for (int ks = 0; ks < 8; ++ks)
        bfrag[ks] = *(const bf16x8*)(wt1 + (wave * 32 + ml) * H + ks * 16 + g * 8);
    const float bias1 = b1[wave * 32 + ml];
    const float bias2 = b2[wave * 32 + ml];

    __syncthreads();

    f32x16 acc;
#pragma unroll
    for (int i = 0; i < 16; ++i) acc[i] = 0.f;

    // GEMM1: C[0:32][wave*32 .. +32]
#pragma unroll
    for (int ks = 0; ks < 8; ++ks) {
        int chunk = (2 * ks + g) ^ (ml & 15);
        bf16x8 afrag = *(const bf16x8*)(&lds[ml * H + (chunk << 3)]);
        acc = __builtin_amdgcn_mfma_f32_32x32x16_bf16(afrag, bfrag[ks], acc, 0, 0, 0);
    }

    __syncthreads();  // all A reads done before T overwrites LDS

    // T = relu(acc + b1) -> LDS (C-layout -> row-major[m][k], swizzled)
#pragma unroll
    for (int reg = 0; reg < 16; ++reg) {
        int rm = (reg & 3) + ((reg >> 2) << 3) + 4 * g;   // 0..31
        int cn = wave * 32 + ml;                           // 0..127
        float v = acc[reg] + bias1;
        v = v > 0.f ? v : 0.f;
        lds[rm * H + ((((cn >> 3) ^ (rm & 15))) << 3) + (cn & 7)] = f2bf(v);
    }

    // B2 fragments
#pragma unroll
    for (int ks = 0; ks < 8; ++ks)
        bfrag[ks] = *(const bf16x8*)(wt2 + (wave * 32 + ml) * H + ks * 16 + g * 8);

#pragma unroll
    for (int i = 0; i < 16; ++i) acc[i] = 0.f;

    __syncthreads();

    // GEMM2
#pragma unroll
    for (int ks = 0; ks < 8; ++ks) {
        int chunk = (2 * ks + g) ^ (ml & 15);
        bf16x8 afrag = *(const bf16x8*)(&lds[ml * H + (chunk << 3)]);
        acc = __builtin_amdgcn_mfma_f32_32x32x16_bf16(afrag, bfrag[ks], acc, 0, 0, 0);
    }

    __syncthreads();  // all T reads done before h overwrites LDS

    // h = relu(acc + b2) -> LDS (same swizzle)
#pragma unroll
    for (int reg = 0; reg < 16; ++reg) {
        int rm = (reg & 3) + ((reg >> 2) << 3) + 4 * g;
        int cn = wave * 32 + ml;
        float v = acc[reg] + bias2;
        v = v > 0.f ? v : 0.f;
        lds[rm * H + ((((cn >> 3) ^ (rm & 15))) << 3) + (cn & 7)] = f2bf(v);
    }

    __syncthreads();

    // coalesced residual update: xw = xr + relu(h); xbout = bf16(xw)
    // 32 rows x 16 chunks = 512 tasks, 2 per thread
#pragma unroll
    for (int i = 0; i < 2; ++i) {
        int ch = tid + 256 * i;
        int r = ch >> 4, c = ch & 15;
        int gr = row0 + r;
        int4 hv = *(const int4*)(&lds[r * H + ((c ^ (r & 15)) << 3)]);
        float4 x0 = *(const float4*)(xr + gr * H + c * 8);
        float4 x1 = *(const float4*)(xr + gr * H + c * 8 + 4);
        x0.x += bflo((u32)hv.x); x0.y += bfhi((u32)hv.x);
        x0.z += bflo((u32)hv.y); x0.w += bfhi((u32)hv.y);
        x1.x += bflo((u32)hv.z); x1.y += bfhi((u32)hv.z);
        x1.z += bflo((u32)hv.w); x1.w += bfhi((u32)hv.w);
        *(float4*)(xw + gr * H + c * 8) = x0;
        *(float4*)(xw + gr * H + c * 8 + 4) = x1;
        int4 xo;
        xo.x = (int)pkbf(x0.x, x0.y);
        xo.y = (int)pkbf(x0.z, x0.w);
        xo.z = (int)pkbf(x1.x, x1.y);
        xo.w = (int)pkbf(x1.z, x1.w);
        *(int4*)(xbout + gr * H + c * 8) = xo;
    }
}

extern "C" void kernel_launch(void* const* d_in, const int* in_sizes, int n_in,
                              void* d_out, int out_size, void* d_ws, size_t ws_size,
                              hipStream_t stream) {
    const float* x_in = (const float*)d_in[0];
    const int* edges = (const int*)d_in[1];
    const float* W1 = (const float*)d_in[2];
    const float* b1 = (const float*)d_in[3];
    const float* W2 = (const float*)d_in[4];
    const float* b2 = (const float*)d_in[5];
    float* x = (float*)d_out;

    char* ws = (char*)d_ws;
    int* gcursor = (int*)(ws + 512);             // 784B      @ 512
    int* offs = (int*)(ws + 4096);               // 400004B   @ 4096
    int* colv = (int*)(ws + 406528);             // 6400000B
    u16* wt = (u16*)(ws + 6809600);              // 262144B
    u16* xb0 = (u16*)(ws + 7072768);             // 25600000B
    u16* xb1 = (u16*)(ws + 32672768);            // 25600000B (end ~58.3MB)
    u32* ebuf = (u32*)xb1;                       // 8.03MB, dead before xb1 written

    hipMemsetAsync(gcursor, 0, NB * sizeof(int), stream);
    preproc_kernel<<<PB_BLOCKS + WT_BLOCKS + XI_BLOCKS, 256, 0, stream>>>(
        edges, gcursor, ebuf, W1, W2, wt, x_in, xb0);
    bfill_kernel<<<NB, 1024, 0, stream>>>(ebuf, gcursor, offs, colv);

    for (int l = 0; l < 4; ++l) {
        u16* xin = (l & 1) ? xb1 : xb0;
        u16* xout = (l & 1) ? xb0 : xb1;
        const float* xr = (l == 0) ? x_in : x;
        mlp_kernel<<<NN / 32, 256, 0, stream>>>(
            xin, colv, offs,
            wt + (l * 2) * 16384, wt + (l * 2 + 1) * 16384,
            b1 + l * 128, b2 + l * 128, xr, x, xout);
    }
}